// Round 1
// baseline (748.873 us; speedup 1.0000x reference)
//
#include <hip/hip_runtime.h>
#include <hip/hip_bf16.h>

#define D_MODEL 1024
#define HEAD    64
#define SEQ     2048
#define BATCH   4
#define ROWS    (BATCH * SEQ)   // 8192

// ---------------------------------------------------------------------------
// Kernel 1: fused QKV projection.  x:[8192,1024] f32, W*:[1024,64], b*:[64]
// -> q,k,v [8192,64] f32 in workspace.
// 256 blocks x 256 threads; 32 rows/block; K staged 64 at a time in LDS.
// W is read directly from global (768 KB total -> L2-resident broadcast).
// ---------------------------------------------------------------------------
__global__ __launch_bounds__(256) void qkv_proj(
    const float* __restrict__ x,
    const float* __restrict__ Wq, const float* __restrict__ bq,
    const float* __restrict__ Wk, const float* __restrict__ bk,
    const float* __restrict__ Wv, const float* __restrict__ bv,
    float* __restrict__ q, float* __restrict__ k, float* __restrict__ v)
{
    __shared__ float Xs[32][68];          // stride 68: 16B-aligned, banks spread

    const int tid  = threadIdx.x;
    const int row0 = blockIdx.x * 32;
    const int tr   = tid >> 4;            // 0..15 -> rows 2*tr, 2*tr+1
    const int tc   = tid & 15;            // cols 4*tc .. 4*tc+3 (per matrix)

    const int lrow = tid >> 3;            // staging: 0..31
    const int lcol = (tid & 7) * 8;       // staging: 0,8,..,56

    float aq[2][4] = {}, ak[2][4] = {}, av[2][4] = {};

    for (int k0 = 0; k0 < D_MODEL; k0 += 64) {
        // ---- stage X[32][64] tile ----
        const float* src = x + (size_t)(row0 + lrow) * D_MODEL + k0 + lcol;
        float4 a0 = *(const float4*)(src);
        float4 a1 = *(const float4*)(src + 4);
        __syncthreads();                  // protect previous tile's readers
        *(float4*)&Xs[lrow][lcol]     = a0;
        *(float4*)&Xs[lrow][lcol + 4] = a1;
        __syncthreads();

        // ---- accumulate ----
        #pragma unroll
        for (int kk = 0; kk < 64; kk += 4) {
            float4 xa = *(const float4*)&Xs[2*tr][kk];
            float4 xb = *(const float4*)&Xs[2*tr + 1][kk];
            float xs0[4] = {xa.x, xa.y, xa.z, xa.w};
            float xs1[4] = {xb.x, xb.y, xb.z, xb.w};
            #pragma unroll
            for (int u = 0; u < 4; ++u) {
                const size_t wrow = (size_t)(k0 + kk + u) * HEAD + tc * 4;
                float4 wq4 = *(const float4*)(Wq + wrow);
                float4 wk4 = *(const float4*)(Wk + wrow);
                float4 wv4 = *(const float4*)(Wv + wrow);
                aq[0][0] += xs0[u]*wq4.x; aq[0][1] += xs0[u]*wq4.y;
                aq[0][2] += xs0[u]*wq4.z; aq[0][3] += xs0[u]*wq4.w;
                aq[1][0] += xs1[u]*wq4.x; aq[1][1] += xs1[u]*wq4.y;
                aq[1][2] += xs1[u]*wq4.z; aq[1][3] += xs1[u]*wq4.w;
                ak[0][0] += xs0[u]*wk4.x; ak[0][1] += xs0[u]*wk4.y;
                ak[0][2] += xs0[u]*wk4.z; ak[0][3] += xs0[u]*wk4.w;
                ak[1][0] += xs1[u]*wk4.x; ak[1][1] += xs1[u]*wk4.y;
                ak[1][2] += xs1[u]*wk4.z; ak[1][3] += xs1[u]*wk4.w;
                av[0][0] += xs0[u]*wv4.x; av[0][1] += xs0[u]*wv4.y;
                av[0][2] += xs0[u]*wv4.z; av[0][3] += xs0[u]*wv4.w;
                av[1][0] += xs1[u]*wv4.x; av[1][1] += xs1[u]*wv4.y;
                av[1][2] += xs1[u]*wv4.z; av[1][3] += xs1[u]*wv4.w;
            }
        }
    }

    // ---- epilogue: bias + store ----
    float4 bq4 = *(const float4*)(bq + tc * 4);
    float4 bk4 = *(const float4*)(bk + tc * 4);
    float4 bv4 = *(const float4*)(bv + tc * 4);
    #pragma unroll
    for (int i = 0; i < 2; ++i) {
        const size_t row = (size_t)(row0 + 2*tr + i);
        float4 oq = {aq[i][0] + bq4.x, aq[i][1] + bq4.y, aq[i][2] + bq4.z, aq[i][3] + bq4.w};
        float4 ok = {ak[i][0] + bk4.x, ak[i][1] + bk4.y, ak[i][2] + bk4.z, ak[i][3] + bk4.w};
        float4 ov = {av[i][0] + bv4.x, av[i][1] + bv4.y, av[i][2] + bv4.z, av[i][3] + bv4.w};
        *(float4*)(q + row * HEAD + tc * 4) = oq;
        *(float4*)(k + row * HEAD + tc * 4) = ok;
        *(float4*)(v + row * HEAD + tc * 4) = ov;
    }
}

// ---------------------------------------------------------------------------
// Kernel 2: causal flash attention, fp32 vector-ALU version.
// Grid (64 q-tiles, 4 batches) x 256 threads.  QB=32, KB=64.
// Thread t: q-row r = t>>3 (8 lanes/row, intra-wave), d/k-slice sub = t&7.
// K tile is XOR-swizzled (d4 ^= row>>3): 8 sub-lanes read rows 8 apart at
// stride 64 -> would be an 8-way bank conflict unswizzled.
// ---------------------------------------------------------------------------
__device__ __forceinline__ int kswz(int row, int d) {
    return ((((d >> 2) ^ (row >> 3)) & 15) << 2) | (d & 3);
}

__global__ __launch_bounds__(256) void attn_fwd(
    const float* __restrict__ q, const float* __restrict__ k,
    const float* __restrict__ v, float* __restrict__ out)
{
    __shared__ float Qs[32][68];
    __shared__ float Ks[64][64];   // swizzled
    __shared__ float Vs[64][64];   // plain: read pattern is conflict-free
    __shared__ float Ps[32][68];

    const int tid = threadIdx.x;
    const int b   = blockIdx.y;
    const int q0  = blockIdx.x * 32;
    const int r   = tid >> 3;      // 0..31
    const int sub = tid & 7;       // 0..7

    const float* qb = q + (size_t)b * SEQ * HEAD;
    const float* kb = k + (size_t)b * SEQ * HEAD;
    const float* vb = v + (size_t)b * SEQ * HEAD;

    // load Q (pre-scaled by 1/sqrt(64))
    {
        const float* src = qb + (size_t)(q0 + r) * HEAD + sub * 8;
        #pragma unroll
        for (int u = 0; u < 8; ++u) Qs[r][sub * 8 + u] = src[u] * 0.125f;
    }

    float m = -3.0e38f, l = 0.0f;
    float acc[8] = {};

    const int ntiles = ((q0 + 31) >> 6) + 1;
    const int qrow   = q0 + r;

    for (int t = 0; t < ntiles; ++t) {
        const int kv0 = t * 64;

        __syncthreads();   // protect prior-tile readers (and publish Qs on t=0)
        {
            const int krow = tid >> 3;          // 0..31
            const int c    = (tid & 7) * 8;
            const float* ksrc0 = kb + (size_t)(kv0 + krow)      * HEAD + c;
            const float* ksrc1 = kb + (size_t)(kv0 + krow + 32) * HEAD + c;
            const float* vsrc0 = vb + (size_t)(kv0 + krow)      * HEAD + c;
            const float* vsrc1 = vb + (size_t)(kv0 + krow + 32) * HEAD + c;
            float4 k00 = *(const float4*)(ksrc0);
            float4 k01 = *(const float4*)(ksrc0 + 4);
            float4 k10 = *(const float4*)(ksrc1);
            float4 k11 = *(const float4*)(ksrc1 + 4);
            *(float4*)&Ks[krow][kswz(krow, c)]            = k00;
            *(float4*)&Ks[krow][kswz(krow, c + 4)]        = k01;
            *(float4*)&Ks[krow + 32][kswz(krow + 32, c)]  = k10;
            *(float4*)&Ks[krow + 32][kswz(krow + 32, c+4)]= k11;
            *(float4*)&Vs[krow][c]          = *(const float4*)(vsrc0);
            *(float4*)&Vs[krow][c + 4]      = *(const float4*)(vsrc0 + 4);
            *(float4*)&Vs[krow + 32][c]     = *(const float4*)(vsrc1);
            *(float4*)&Vs[krow + 32][c + 4] = *(const float4*)(vsrc1 + 4);
        }
        __syncthreads();

        // ---- S = (Q/8) . K^T  for this thread's 8 k-columns ----
        float s[8] = {};
        #pragma unroll
        for (int d = 0; d < 64; d += 4) {
            float4 q4 = *(const float4*)&Qs[r][d];
            #pragma unroll
            for (int jj = 0; jj < 8; ++jj) {
                const int row = sub * 8 + jj;
                float4 k4 = *(const float4*)&Ks[row][kswz(row, d)];
                s[jj] += q4.x*k4.x + q4.y*k4.y + q4.z*k4.z + q4.w*k4.w;
            }
        }

        // ---- causal mask ----
        const bool full = (kv0 + 63 <= q0);
        if (!full) {
            #pragma unroll
            for (int jj = 0; jj < 8; ++jj)
                if (kv0 + sub * 8 + jj > qrow) s[jj] = -3.0e38f;
        }

        // ---- online softmax (row spread over 8 lanes) ----
        float tm = s[0];
        #pragma unroll
        for (int jj = 1; jj < 8; ++jj) tm = fmaxf(tm, s[jj]);
        tm = fmaxf(tm, __shfl_xor(tm, 1, 64));
        tm = fmaxf(tm, __shfl_xor(tm, 2, 64));
        tm = fmaxf(tm, __shfl_xor(tm, 4, 64));

        const float mnew = fmaxf(m, tm);
        const float corr = __expf(m - mnew);
        float p[8], psum = 0.0f;
        #pragma unroll
        for (int jj = 0; jj < 8; ++jj) { p[jj] = __expf(s[jj] - mnew); psum += p[jj]; }
        psum += __shfl_xor(psum, 1, 64);
        psum += __shfl_xor(psum, 2, 64);
        psum += __shfl_xor(psum, 4, 64);
        l = l * corr + psum;
        m = mnew;

        float4 p0 = {p[0], p[1], p[2], p[3]};
        float4 p1 = {p[4], p[5], p[6], p[7]};
        *(float4*)&Ps[r][sub * 8]     = p0;
        *(float4*)&Ps[r][sub * 8 + 4] = p1;

        #pragma unroll
        for (int dd = 0; dd < 8; ++dd) acc[dd] *= corr;

        __syncthreads();   // publish Ps across the block (conservative)

        // ---- O += P . V  for this thread's 8 head-dims ----
        #pragma unroll
        for (int j4 = 0; j4 < 64; j4 += 4) {
            float4 p4 = *(const float4*)&Ps[r][j4];
            float pj[4] = {p4.x, p4.y, p4.z, p4.w};
            #pragma unroll
            for (int u = 0; u < 4; ++u) {
                float4 va = *(const float4*)&Vs[j4 + u][sub * 8];
                float4 vb2 = *(const float4*)&Vs[j4 + u][sub * 8 + 4];
                acc[0] += pj[u]*va.x;  acc[1] += pj[u]*va.y;
                acc[2] += pj[u]*va.z;  acc[3] += pj[u]*va.w;
                acc[4] += pj[u]*vb2.x; acc[5] += pj[u]*vb2.y;
                acc[6] += pj[u]*vb2.z; acc[7] += pj[u]*vb2.w;
            }
        }
    }

    // ---- epilogue ----
    const float inv = 1.0f / l;
    float4 o0 = {acc[0]*inv, acc[1]*inv, acc[2]*inv, acc[3]*inv};
    float4 o1 = {acc[4]*inv, acc[5]*inv, acc[6]*inv, acc[7]*inv};
    float* dst = out + (size_t)b * SEQ * HEAD + (size_t)qrow * HEAD + sub * 8;
    *(float4*)(dst)     = o0;
    *(float4*)(dst + 4) = o1;
}

// ---------------------------------------------------------------------------
extern "C" void kernel_launch(void* const* d_in, const int* in_sizes, int n_in,
                              void* d_out, int out_size, void* d_ws, size_t ws_size,
                              hipStream_t stream) {
    const float* x  = (const float*)d_in[0];
    const float* Wq = (const float*)d_in[1];
    const float* bq = (const float*)d_in[2];
    const float* Wk = (const float*)d_in[3];
    const float* bk = (const float*)d_in[4];
    const float* Wv = (const float*)d_in[5];
    const float* bv = (const float*)d_in[6];

    float* qw = (float*)d_ws;
    float* kw = qw + (size_t)ROWS * HEAD;
    float* vw = kw + (size_t)ROWS * HEAD;
    float* o  = (float*)d_out;

    qkv_proj<<<dim3(ROWS / 32), dim3(256), 0, stream>>>(
        x, Wq, bq, Wk, bk, Wv, bv, qw, kw, vw);

    attn_fwd<<<dim3(SEQ / 32, BATCH), dim3(256), 0, stream>>>(qw, kw, vw, o);
}